// Round 2
// baseline (8044.685 us; speedup 1.0000x reference)
//
#include <hip/hip_runtime.h>
#include <hip/hip_bf16.h>

#define NPTS 8192
#define SDIM 5
#define NBATCH 4
#define NS 4096
#define FEAT 64
#define KNN 3

// Pin a value to a VGPR so the compiler cannot contract mul+add into FMA
// (we must match numpy's separate-mul-then-add f32 rounding for argmax/top-k
// index stability).
#define NOFUSE(x) asm volatile("" : "+v"(x))

__device__ __forceinline__ float sqdist5(float p0, float p1, float p2, float p3, float p4,
                                         float q0, float q1, float q2, float q3, float q4)
{
    float d0 = p0 - q0, d1 = p1 - q1, d2 = p2 - q2, d3 = p3 - q3, d4 = p4 - q4;
    float m0 = d0 * d0; NOFUSE(m0);
    float m1 = d1 * d1; NOFUSE(m1);
    float m2 = d2 * d2; NOFUSE(m2);
    float m3 = d3 * d3; NOFUSE(m3);
    float m4 = d4 * d4; NOFUSE(m4);
    float a = m0 + m1;  // numpy sum order for n=5: sequential left-assoc
    a = a + m2;
    a = a + m3;
    a = a + m4;
    return a;
}

// ---------------------------------------------------------------------------
// Kernel 1: farthest point sampling. One 1024-thread block per batch.
// Each thread owns 8 strided points (idx = j*1024 + t) in registers.
// Per step: scalar-load last point's coords, min-update dists, block argmax
// (tie-break lowest index, matching jnp.argmax), 2 barriers.
// ---------------------------------------------------------------------------
__global__ __launch_bounds__(1024)
void fps_kernel(const float* __restrict__ spatial, int* __restrict__ sidx)
{
    const int b = blockIdx.x;
    const int t = threadIdx.x;
    const float* pts = spatial + (size_t)b * NPTS * SDIM;

    float px0[8], px1[8], px2[8], px3[8], px4[8];
    float dist[8];
#pragma unroll
    for (int j = 0; j < 8; ++j) {
        const int i = j * 1024 + t;
        px0[j] = pts[i * SDIM + 0];
        px1[j] = pts[i * SDIM + 1];
        px2[j] = pts[i * SDIM + 2];
        px3[j] = pts[i * SDIM + 3];
        px4[j] = pts[i * SDIM + 4];
        dist[j] = __builtin_inff();
    }
    if (t == 0) dist[0] = -__builtin_inff();   // point 0 pre-selected

    __shared__ unsigned long long s_wave[16];
    __shared__ int s_sel;

    if (t == 0) sidx[b * NS] = 0;
    int bsel = 0;

    for (int step = 1; step < NS; ++step) {
        const float* qp = pts + bsel * SDIM;   // bsel uniform -> scalar loads
        const float q0 = qp[0], q1 = qp[1], q2 = qp[2], q3 = qp[3], q4 = qp[4];

        float bestv = -__builtin_inff();
        int   besti = 0;
#pragma unroll
        for (int j = 0; j < 8; ++j) {
            float a  = sqdist5(px0[j], px1[j], px2[j], px3[j], px4[j],
                               q0, q1, q2, q3, q4);
            float nd = fminf(dist[j], a);
            dist[j] = nd;
            // j ascending => index ascending: strict '>' keeps lowest index on ties
            if (nd > bestv) { bestv = nd; besti = j * 1024 + t; }
        }
        // wave-level argmax (64 lanes), tie-break lower index
#pragma unroll
        for (int off = 32; off > 0; off >>= 1) {
            float ov = __shfl_xor(bestv, off);
            int   oi = __shfl_xor(besti, off);
            if (ov > bestv || (ov == bestv && oi < besti)) { bestv = ov; besti = oi; }
        }
        if ((t & 63) == 0) {
            // monotone float->uint key; selected points (-inf) map to 0.
            // Higher dist => larger key; equal dist => smaller index wins.
            unsigned int kv = (bestv < 0.0f) ? 0u
                                             : (__float_as_uint(bestv) | 0x80000000u);
            s_wave[t >> 6] = ((unsigned long long)kv << 32) |
                             (unsigned long long)(0xFFFFFFFFu - (unsigned)besti);
        }
        __syncthreads();
        if (t < 64) {
            unsigned long long kk = (t < 16) ? s_wave[t] : 0ull;
#pragma unroll
            for (int off = 8; off > 0; off >>= 1) {
                unsigned long long o = __shfl_xor(kk, off);
                if (o > kk) kk = o;
            }
            if (t == 0) {
                const int sel = (int)(0xFFFFFFFFu - (unsigned int)(kk & 0xFFFFFFFFull));
                s_sel = sel;
                sidx[b * NS + step] = sel;
            }
        }
        __syncthreads();
        bsel = __builtin_amdgcn_readfirstlane(s_sel);
        const int  jj  = bsel >> 10;
        const bool own = (bsel & 1023) == t;
#pragma unroll
        for (int j = 0; j < 8; ++j)          // static indexing only (no scratch)
            if (own && j == jj) dist[j] = -__builtin_inff();
    }
}

// ---------------------------------------------------------------------------
// Kernel 2: kNN (K=3) of each sampled point over the full cloud.
// 256 threads/block = 32 sampled points x 8 stripes; stripe r covers i%8==r.
// Packed u64 keys (d_bits<<32 | idx): ascending key == lax.top_k order.
// ---------------------------------------------------------------------------
__global__ __launch_bounds__(256)
void knn_kernel(const float* __restrict__ spatial, const int* __restrict__ sidx,
                int* __restrict__ knn)
{
    const int t   = threadIdx.x;
    const int sl  = t >> 3;
    const int r   = t & 7;
    const int spb = NS / 32;                 // 128 blocks per batch
    const int b   = blockIdx.x / spb;
    const int s   = (blockIdx.x % spb) * 32 + sl;
    const int self = sidx[b * NS + s];
    const float* pts = spatial + (size_t)b * NPTS * SDIM;

    const float q0 = pts[self * SDIM + 0], q1 = pts[self * SDIM + 1],
                q2 = pts[self * SDIM + 2], q3 = pts[self * SDIM + 3],
                q4 = pts[self * SDIM + 4];

    unsigned long long k0 = ~0ull, k1 = ~0ull, k2 = ~0ull;
    for (int i = r; i < NPTS; i += 8) {
        float a = sqdist5(pts[i * SDIM + 0], pts[i * SDIM + 1], pts[i * SDIM + 2],
                          pts[i * SDIM + 3], pts[i * SDIM + 4],
                          q0, q1, q2, q3, q4);
        unsigned long long key = ((unsigned long long)__float_as_uint(a) << 32) |
                                 (unsigned long long)(unsigned)i;
        if (i == self) key = ~0ull;          // reference sets self-distance to inf
        if (key < k2) {
            if (key < k1) {
                k2 = k1;
                if (key < k0) { k1 = k0; k0 = key; } else k1 = key;
            } else k2 = key;
        }
    }

    __shared__ unsigned long long sk[256][3];
    sk[t][0] = k0; sk[t][1] = k1; sk[t][2] = k2;
    __syncthreads();

    if (r == 0) {
        unsigned long long b0 = ~0ull, b1 = ~0ull, b2 = ~0ull;
        for (int rr = 0; rr < 8; ++rr) {
#pragma unroll
            for (int m = 0; m < 3; ++m) {
                unsigned long long key = sk[(sl << 3) | rr][m];
                if (key < b2) {
                    if (key < b1) {
                        b2 = b1;
                        if (key < b0) { b1 = b0; b0 = key; } else b1 = key;
                    } else b2 = key;
                }
            }
        }
        const int base = (b * NS + s) * KNN;
        knn[base + 0] = (int)(b0 & 0xFFFFFFFFull);
        knn[base + 1] = (int)(b1 & 0xFFFFFFFFull);
        knn[base + 2] = (int)(b2 & 0xFFFFFFFFull);
    }
}

// ---------------------------------------------------------------------------
// Kernel 3: gather neighbor features -> second output region (f32).
// ---------------------------------------------------------------------------
__global__ __launch_bounds__(256)
void gather_kernel(const float* __restrict__ x, const int* __restrict__ knn,
                   float* __restrict__ out2)
{
    const long long tid = (long long)blockIdx.x * 256 + threadIdx.x;
    const int       f   = (int)(tid & 63);
    const long long row = tid >> 6;                  // b*NS*KNN + s*KNN + k
    const int       idx = knn[row];
    const int       b   = (int)(row / (NS * KNN));
    out2[tid] = x[((size_t)b * NPTS + idx) * FEAT + f];
}

// ---------------------------------------------------------------------------
// Kernel 4a: transpose the 7 weight matrices to [in][out] for coalesced matvec.
// ---------------------------------------------------------------------------
__global__ __launch_bounds__(256)
void transpose_w(const float* __restrict__ w0, const float* __restrict__ w1,
                 const float* __restrict__ w2, const float* __restrict__ w3,
                 const float* __restrict__ w4, const float* __restrict__ w5,
                 const float* __restrict__ w6, float* __restrict__ wt)
{
    const float* w;
    switch (blockIdx.x) {
        case 0: w = w0; break; case 1: w = w1; break; case 2: w = w2; break;
        case 3: w = w3; break; case 4: w = w4; break; case 5: w = w5; break;
        default: w = w6; break;
    }
    float* o = wt + blockIdx.x * 4096;
    for (int e = threadIdx.x; e < 4096; e += 256) {
        const int r = e >> 6, c = e & 63;            // r = out idx, c = in idx
        o[c * 64 + r] = w[e];
    }
}

// ---------------------------------------------------------------------------
// Kernel 4b: per-point vector attention MLP chain. One wave per sampled point,
// lane = channel; 64-wide matvecs via lane-broadcast shuffles.
// ---------------------------------------------------------------------------
__global__ __launch_bounds__(256)
void attn_kernel(const float* __restrict__ x, const int* __restrict__ sidx,
                 const float* __restrict__ wt,
                 const float* __restrict__ b_in, const float* __restrict__ b_q,
                 const float* __restrict__ b_k, const float* __restrict__ b_v,
                 const float* __restrict__ b_h1, const float* __restrict__ b_h2,
                 const float* __restrict__ b_out,
                 float* __restrict__ out)
{
    const int lane = threadIdx.x & 63;
    const int wid  = (int)((blockIdx.x * 256 + threadIdx.x) >> 6);  // point id
    const int b    = wid >> 12;                                      // /NS
    const int si   = sidx[wid];
    const float xs = x[((size_t)b * NPTS + si) * FEAT + lane];

    const float* wt_in  = wt;
    const float* wt_q   = wt + 4096;
    const float* wt_k   = wt + 2 * 4096;
    const float* wt_v   = wt + 3 * 4096;
    const float* wt_h1  = wt + 4 * 4096;
    const float* wt_h2  = wt + 5 * 4096;
    const float* wt_out = wt + 6 * 4096;

    float tv = b_in[lane];
#pragma unroll
    for (int i = 0; i < 64; ++i) tv = fmaf(wt_in[i * 64 + lane], __shfl(xs, i), tv);

    float q = b_q[lane], k = b_k[lane], v = b_v[lane];
#pragma unroll
    for (int i = 0; i < 64; ++i) {
        const float ti = __shfl(tv, i);
        q = fmaf(wt_q[i * 64 + lane], ti, q);
        k = fmaf(wt_k[i * 64 + lane], ti, k);
        v = fmaf(wt_v[i * 64 + lane], ti, v);
    }
    const float d = q - k;
    float h = b_h1[lane];
#pragma unroll
    for (int i = 0; i < 64; ++i) h = fmaf(wt_h1[i * 64 + lane], __shfl(d, i), h);
    h = fmaxf(h, 0.0f);
    float h2 = b_h2[lane];
#pragma unroll
    for (int i = 0; i < 64; ++i) h2 = fmaf(wt_h2[i * 64 + lane], __shfl(h, i), h2);

    // softmax over the 64 channels (one wave)
    float m = h2;
#pragma unroll
    for (int off = 32; off > 0; off >>= 1) m = fmaxf(m, __shfl_xor(m, off));
    const float e = expf(h2 - m);
    float sum = e;
#pragma unroll
    for (int off = 32; off > 0; off >>= 1) sum += __shfl_xor(sum, off);
    const float u = (e / sum) * v;

    float o = b_out[lane];
#pragma unroll
    for (int i = 0; i < 64; ++i) o = fmaf(wt_out[i * 64 + lane], __shfl(u, i), o);
    o += xs;   // residual

    out[(size_t)wid * FEAT + lane] = o;
}

// ---------------------------------------------------------------------------
extern "C" void kernel_launch(void* const* d_in, const int* in_sizes, int n_in,
                              void* d_out, int out_size, void* d_ws, size_t ws_size,
                              hipStream_t stream)
{
    const float* x       = (const float*)d_in[0];
    const float* spatial = (const float*)d_in[1];
    const float* w_in    = (const float*)d_in[2];
    const float* b_in    = (const float*)d_in[3];
    const float* w_q     = (const float*)d_in[4];
    const float* b_q     = (const float*)d_in[5];
    const float* w_k     = (const float*)d_in[6];
    const float* b_k     = (const float*)d_in[7];
    const float* w_v     = (const float*)d_in[8];
    const float* b_v     = (const float*)d_in[9];
    const float* w_h1    = (const float*)d_in[10];
    const float* b_h1    = (const float*)d_in[11];
    const float* w_h2    = (const float*)d_in[12];
    const float* b_h2    = (const float*)d_in[13];
    const float* w_out   = (const float*)d_in[14];
    const float* b_out   = (const float*)d_in[15];

    int*   sidx = (int*)d_ws;                                  // 4*4096 ints
    int*   knn  = (int*)((char*)d_ws + 65536);                 // 4*4096*3 ints
    float* wt   = (float*)((char*)d_ws + 65536 + 196608);      // 7*4096 floats

    float* out  = (float*)d_out;
    float* out2 = out + (size_t)NBATCH * NS * FEAT;

    hipLaunchKernelGGL(fps_kernel, dim3(NBATCH), dim3(1024), 0, stream,
                       spatial, sidx);
    hipLaunchKernelGGL(transpose_w, dim3(7), dim3(256), 0, stream,
                       w_in, w_q, w_k, w_v, w_h1, w_h2, w_out, wt);
    hipLaunchKernelGGL(knn_kernel, dim3(NBATCH * NS / 32), dim3(256), 0, stream,
                       spatial, sidx, knn);
    hipLaunchKernelGGL(gather_kernel, dim3(NBATCH * NS * KNN * FEAT / 256), dim3(256),
                       0, stream, x, knn, out2);
    hipLaunchKernelGGL(attn_kernel, dim3(NBATCH * NS * FEAT / 256), dim3(256),
                       0, stream, x, sidx, wt,
                       b_in, b_q, b_k, b_v, b_h1, b_h2, b_out, out);
}